// Round 18
// baseline (154.581 us; speedup 1.0000x reference)
//
#include <hip/hip_runtime.h>
#include <hip/hip_bf16.h>
#include <stdint.h>

#define B_ 8
#define C_ 2048
#define E_ 1024
#define H_ 128
#define M_ (B_*C_)      // 16384 rows total
#define SLOTS_B 144     // chunks per batch: sum_j ceil((j+1)/4), j<32

typedef __attribute__((ext_vector_type(8))) short bf16x8;
typedef __attribute__((ext_vector_type(4))) float f32x4;

__device__ __forceinline__ unsigned short f2bf(float f) {
    union { float f; unsigned int u; } v; v.f = f;
    unsigned int u = v.u;
    u += 0x7fff + ((u >> 16) & 1);   // RNE
    return (unsigned short)(u >> 16);
}
__device__ __forceinline__ float bf2f(unsigned short u) {
    union { unsigned int i; float f; } v; v.i = ((unsigned int)u) << 16; return v.f;
}
// pack two floats -> two bf16 (round-half-up) in ONE v_perm + 2 adds
__device__ __forceinline__ unsigned int pack2bf(float lo, float hi) {
    union { float f; unsigned int u; } a, b; a.f = lo; b.f = hi;
    return __builtin_amdgcn_perm(b.u + 0x8000u, a.u + 0x8000u, 0x07060302);
}
// constant fragment the compiler cannot fold/hoist-analyze (runtime v_mov)
__device__ __forceinline__ bf16x8 cstf() {
    union { unsigned int u[4]; bf16x8 v; } x;
#pragma unroll
    for (int i = 0; i < 4; ++i)
        asm volatile("v_mov_b32 %0, 0x3f803f80" : "=v"(x.u[i]));
    return x.v;
}
// keep a fragment live without cost (anti-DCE, rule #17)
__device__ __forceinline__ void sinkf(const bf16x8& v) {
    union { bf16x8 v; unsigned int u[4]; } x; x.v = v;
    asm volatile("" :: "v"(x.u[0]), "v"(x.u[1]), "v"(x.u[2]), "v"(x.u[3]));
}

#define GLOAD_LDS16(g, l) \
    __builtin_amdgcn_global_load_lds((const __attribute__((address_space(1))) void*)(g), \
                                     (__attribute__((address_space(3))) void*)(l), 16, 0, 0)

// -------- W -> wave-contiguous fragment layout WT3 --------------------------
__global__ __launch_bounds__(256) void wt3_kernel(const float* __restrict__ Wq,
                                                  const float* __restrict__ Wk,
                                                  const float* __restrict__ Wv,
                                                  unsigned short* __restrict__ WT3) {
    int z = blockIdx.y;
    const float* W = (z == 0) ? Wq : (z == 1) ? Wk : Wv;
    unsigned short* o = WT3 + (size_t)z * H_ * E_;
    int g = blockIdx.x * 256 + threadIdx.x;     // granule id, 0..16383
    int lrow = g & 15;
    int lq   = (g >> 4) & 3;
    int ni   = (g >> 6) & 1;
    int wid  = (g >> 7) & 3;
    int ks   = (g >> 9) & 1;
    int t    = g >> 10;
    int k = t * 64 + ks * 32 + lq * 8;
    int h = wid * 32 + ni * 16 + lrow;
    unsigned short v[8];
#pragma unroll
    for (int j = 0; j < 8; ++j)
        v[j] = f2bf(W[(size_t)(k + j) * H_ + h]);
    *(bf16x8*)&o[(size_t)g * 8] = *(const bf16x8*)v;
}

#define MF(a, b, c) __builtin_amdgcn_mfma_f32_16x16x32_bf16((a), (b), (c), 0, 0, 0)

// ------ proj body, templated ablation: UB=B loads, UAL=A gloads, UAR=A LDS
// reads+convert, UM=MFMA. <1,1,1,1> == the real kernel structure (r17 form).
template <int UB, int UAL, int UAR, int UM>
__global__ __launch_bounds__(256) void proj_t(const float* __restrict__ x,
                                              const unsigned short* __restrict__ WT3,
                                              unsigned short* __restrict__ QKV) {
    __shared__ __align__(16) float Asf[3][32][64];    // 24 KB

    const int tid = threadIdx.x;
    const int wid = tid >> 6, lane = tid & 63;
    const int lrow = lane & 15, lq = lane >> 4;
    const int wcol = wid * 32;
    const int row0 = blockIdx.x * 32;
    const unsigned short* wbase = WT3 + (size_t)wid * 1024 + (size_t)lane * 8;

    const int srow = tid >> 4;
    const int slotL = tid & 15;

    auto ASTAGE = [&](int buf, int t) {
#pragma unroll
        for (int s = 0; s < 2; ++s) {
            int row = s * 16 + srow;
            const float* src = x + (size_t)(row0 + row) * E_ + t * 64
                             + ((slotL ^ (row & 7)) * 4);
            GLOAD_LDS16(src, (char*)&Asf[buf][0][0] + s * 4096 + tid * 16);
        }
    };

    f32x4 acc[3][2][2];
#pragma unroll
    for (int w = 0; w < 3; ++w)
#pragma unroll
        for (int mi = 0; mi < 2; ++mi)
#pragma unroll
            for (int ni = 0; ni < 2; ++ni) acc[w][mi][ni] = (f32x4){0.f, 0.f, 0.f, 0.f};

    bf16x8 cb = cstf();   // constant frag for disabled paths

    if constexpr (UAL) {
        ASTAGE(0, 0);
        ASTAGE(1, 1);
        asm volatile("s_waitcnt vmcnt(2)" ::: "memory");
    }

    for (int t = 0; t < 16; ++t) {
        const int a0 = t % 3;
        __builtin_amdgcn_s_barrier();
        __builtin_amdgcn_sched_barrier(0);

        bf16x8 bw[3][2][2];
        if constexpr (UB) {
            const unsigned short* wp = wbase + (size_t)t * 8192;
#pragma unroll
            for (int w = 0; w < 3; ++w)
#pragma unroll
                for (int ks = 0; ks < 2; ++ks)
#pragma unroll
                    for (int ni = 0; ni < 2; ++ni)
                        bw[w][ks][ni] = *(const bf16x8*)(wp + (size_t)w * 131072 + ks * 4096 + ni * 512);
        } else {
#pragma unroll
            for (int w = 0; w < 3; ++w)
#pragma unroll
                for (int ks = 0; ks < 2; ++ks)
#pragma unroll
                    for (int ni = 0; ni < 2; ++ni) bw[w][ks][ni] = cb;
        }
        __builtin_amdgcn_sched_barrier(0);

        if constexpr (UAL) { if (t < 14) ASTAGE((t + 2) % 3, t + 2); }
        __builtin_amdgcn_sched_barrier(0);

        bf16x8 af[2][2];
        if constexpr (UAR) {
#pragma unroll
            for (int mi = 0; mi < 2; ++mi)
#pragma unroll
                for (int ks = 0; ks < 2; ++ks) {
                    int row = mi * 16 + lrow;
                    int m7 = row & 7;
                    int s0 = 2 * (ks * 4 + lq);
                    f32x4 f0 = *(const f32x4*)&Asf[a0][row][((s0)     ^ m7) * 4];
                    f32x4 f1 = *(const f32x4*)&Asf[a0][row][((s0 + 1) ^ m7) * 4];
                    union { unsigned int u[4]; bf16x8 v; } pk;
                    pk.u[0] = pack2bf(f0[0], f0[1]);
                    pk.u[1] = pack2bf(f0[2], f0[3]);
                    pk.u[2] = pack2bf(f1[0], f1[1]);
                    pk.u[3] = pack2bf(f1[2], f1[3]);
                    af[mi][ks] = pk.v;
                }
        } else {
#pragma unroll
            for (int mi = 0; mi < 2; ++mi)
#pragma unroll
                for (int ks = 0; ks < 2; ++ks) af[mi][ks] = cb;
        }

        if constexpr (UM) {
            __builtin_amdgcn_s_setprio(1);
#pragma unroll
            for (int ks = 0; ks < 2; ++ks)
#pragma unroll
                for (int w = 0; w < 3; ++w)
#pragma unroll
                    for (int ni = 0; ni < 2; ++ni)
#pragma unroll
                        for (int mi = 0; mi < 2; ++mi)
                            acc[w][mi][ni] = MF(af[mi][ks], bw[w][ks][ni], acc[w][mi][ni]);
            __builtin_amdgcn_s_setprio(0);
        } else {
#pragma unroll
            for (int mi = 0; mi < 2; ++mi)
#pragma unroll
                for (int ks = 0; ks < 2; ++ks) sinkf(af[mi][ks]);
#pragma unroll
            for (int w = 0; w < 3; ++w)
#pragma unroll
                for (int ks = 0; ks < 2; ++ks)
#pragma unroll
                    for (int ni = 0; ni < 2; ++ni) sinkf(bw[w][ks][ni]);
        }
    }

    // epilogue (keeps acc live in all variants; real variant writes real data)
#pragma unroll
    for (int w = 0; w < 2; ++w) {
        const float qs = (w == 0) ? 0.03125f : 1.0f;
        unsigned short* outp = QKV + (size_t)w * M_ * H_;
#pragma unroll
        for (int mi = 0; mi < 2; ++mi) {
            int r0 = row0 + mi * 16 + lq * 4;
#pragma unroll
            for (int ni = 0; ni < 2; ++ni) {
                int col = wcol + ni * 16 + lrow;
#pragma unroll
                for (int r = 0; r < 4; ++r)
                    outp[(size_t)(r0 + r) * H_ + col] = f2bf(acc[w][mi][ni][r] * qs);
            }
        }
    }
    {
        unsigned short* vt = QKV + (size_t)2 * M_ * H_;
        int b = row0 / C_;
        int cbase = row0 % C_;
#pragma unroll
        for (int mi = 0; mi < 2; ++mi) {
            int c0 = cbase + mi * 16 + lq * 4;
#pragma unroll
            for (int ni = 0; ni < 2; ++ni) {
                int h = wcol + ni * 16 + lrow;
                __align__(8) unsigned short p[4] = {f2bf(acc[2][mi][ni][0]), f2bf(acc[2][mi][ni][1]),
                                                    f2bf(acc[2][mi][ni][2]), f2bf(acc[2][mi][ni][3])};
                *(uint2*)&vt[((size_t)b * H_ + h) * C_ + c0] = *(const uint2*)p;
            }
        }
    }
}

// ---------------- split-KV flash attention, swapped-QK lane-local softmax ----
__global__ __launch_bounds__(256) void attn_kernel(const unsigned short* __restrict__ QKV,
                                                   unsigned short* __restrict__ PO,
                                                   float* __restrict__ ML,
                                                   float* __restrict__ out) {
    __shared__ __align__(16) unsigned short Ks[2][64][128];
    __shared__ __align__(16) unsigned short Vt[2][128][64];

    const unsigned short* Q  = QKV;
    const unsigned short* K  = QKV + (size_t)M_ * H_;
    const unsigned short* VT = QKV + (size_t)2 * M_ * H_;

    const int tid = threadIdx.x, wid = tid >> 6, lane = tid & 63;
    const int lrow = lane & 15, lq = lane >> 4, lk = lq * 8;
    const int b = blockIdx.x;
    const int rr = blockIdx.y;

    int j = 0;
#pragma unroll
    for (int jj = 1; jj < 32; ++jj) {
        int q = jj >> 2, s = jj & 3;
        if (jj + 2 * q * (q - 1) + s * q <= rr) j = jj;
    }
    const int qj = j >> 2, sj = j & 3;
    const int Cj = j + 2 * qj * (qj - 1) + sj * qj;
    const int c = rr - Cj;
    const int nch = qj + 1;
    const int t0 = c * 4;
    const int t1 = min(t0 + 4, j + 1);

    const int q0w = j * 64 + wid * 16;
    const unsigned short* Kb  = K  + (size_t)b * C_ * H_;
    const unsigned short* VTb = VT + (size_t)b * H_ * C_;
    const int qabs = q0w + lrow;

    const int krow = tid >> 4, kg = tid & 15;
    const int vrow = tid >> 3, vg = tid & 7;

    bf16x8 qf[4];
#pragma unroll
    for (int kf = 0; kf < 4; ++kf)
        qf[kf] = *(const bf16x8*)&Q[((size_t)b * C_ + q0w + lrow) * H_ + kf * 32 + lk];

    f32x4 o[8];
#pragma unroll
    for (int nf = 0; nf < 8; ++nf) o[nf] = (f32x4){0.f, 0.f, 0.f, 0.f};
    float m = -INFINITY, l = 0.f;

    auto STAGE = [&](int buf, int t) {
        const int kv0 = t * 64;
#pragma unroll
        for (int s = 0; s < 4; ++s) {
            int r = s * 16 + krow;
            int prow = ((r & 0x10) << 1) | ((r & 0x0C) << 1) | ((r & 0x20) >> 3) | (r & 3);
            GLOAD_LDS16(&Kb[(size_t)(kv0 + prow) * H_ + ((kg ^ (r & 15)) * 8)],
                        (char*)&Ks[buf][0][0] + s * 4096 + tid * 16);
        }
#pragma unroll
        for (int s = 0; s < 4; ++s) {
            int h = s * 32 + vrow;
            GLOAD_LDS16(&VTb[(size_t)h * C_ + kv0 + ((vg ^ (h & 7)) * 8)],
                        (char*)&Vt[buf][0][0] + s * 4096 + tid * 16);
        }
    };

    STAGE(0, t0);

    for (int t = t0; t < t1; ++t) {
        const int cur = (t - t0) & 1;
        __syncthreads();
        if (t + 1 < t1) STAGE(cur ^ 1, t + 1);

        const int kv0 = t * 64;
        f32x4 s[4];
        __builtin_amdgcn_s_setprio(1);
#pragma unroll
        for (int nf = 0; nf < 4; ++nf) {
            s[nf] = (f32x4){0.f, 0.f, 0.f, 0.f};
            const int rk = nf * 16 + lrow;
#pragma unroll
            for (int kf = 0; kf < 4; ++kf) {
                bf16x8 kb = *(const bf16x8*)&Ks[cur][rk][((kf * 4 + lq) ^ (rk & 15)) * 8];
                s[nf] = __builtin_amdgcn_mfma_f32_16x16x32_bf16(kb, qf[kf], s[nf], 0, 0, 0); // SWAPPED
            }
        }
        __builtin_amdgcn_s_setprio(0);
        bf16x8 vb[8][2];
#pragma unroll
        for (int nf = 0; nf < 8; ++nf) {
            const int h = nf * 16 + lrow;
#pragma unroll
            for (int kf2 = 0; kf2 < 2; ++kf2)
                vb[nf][kf2] = *(const bf16x8*)&Vt[cur][h][((kf2 * 4 + lq) ^ (h & 7)) * 8];
        }

        if (t == j) {
#pragma unroll
            for (int nf = 0; nf < 4; ++nf) {
                int kvb = kv0 + ((nf & 1) << 5) + (lq << 3) + ((nf >> 1) << 2);
#pragma unroll
                for (int r = 0; r < 4; ++r)
                    if (kvb + r > qabs) s[nf][r] = -INFINITY;
            }
        }
        float mt = s[0][0];
#pragma unroll
        for (int nf = 0; nf < 4; ++nf)
#pragma unroll
            for (int r = 0; r < 4; ++r) mt = fmaxf(mt, s[nf][r]);
        mt = fmaxf(mt, __shfl_xor(mt, 16));
        mt = fmaxf(mt, __shfl_xor(mt, 32));

        float mn = fmaxf(m, mt);
        float corr = __expf(m - mn);
        m = mn;

        float p[4][4];
        float ps = 0.f;
#pragma unroll
        for (int nf = 0; nf < 4; ++nf)
#pragma unroll
            for (int r = 0; r < 4; ++r) {
                float e = __expf(s[nf][r] - mn);
                p[nf][r] = e;
                ps += e;
            }
        ps += __shfl_xor(ps, 16);
        ps += __shfl_xor(ps, 32);
        l = l * corr + ps;

        float corr4[4];
#pragma unroll
        for (int r = 0; r < 4; ++r)
            corr4[r] = __shfl(corr, (lane & 48) | (lq * 4 + r));
#pragma unroll
        for (int nf = 0; nf < 8; ++nf)
#pragma unroll
            for (int r = 0; r < 4; ++r) o[nf][r] *= corr4[r];

        bf16x8 pa[2];
#pragma unroll
        for (int kf2 = 0; kf2 < 2; ++kf2) {
            union { unsigned int u[4]; bf16x8 v; } pk;
            pk.u[0] = pack2bf(p[kf2][0],     p[kf2][1]);
            pk.u[1] = pack2bf(p[kf2][2],     p[kf2][3]);
            pk.u[2] = pack2bf(p[kf2 + 2][0], p[kf2 + 2][1]);
            pk.u[3] = pack2bf(p[kf2 + 2][2], p[kf2 + 2][3]);
            pa[kf2] = pk.v;
        }
        __builtin_amdgcn_s_setprio(1);
#pragma unroll
        for (int nf = 0; nf < 8; ++nf)
#pragma unroll
            for (int kf2 = 0; kf2 < 2; ++kf2)
                o[nf] = __builtin_amdgcn_mfma_f32_16x16x32_bf16(pa[kf2], vb[nf][kf2], o[nf], 0, 0, 0);
        __builtin_amdgcn_s_setprio(0);
    }

    float l4[4], m4[4];
#pragma unroll
    for (int r = 0; r < 4; ++r) {
        l4[r] = __shfl(l, (lane & 48) | (lq * 4 + r));
        m4[r] = __shfl(m, (lane & 48) | (lq * 4 + r));
    }
    const int qrow0 = q0w + lq * 4;

    if (nch == 1) {
#pragma unroll
        for (int nf = 0; nf < 8; ++nf) {
            int col = nf * 16 + lrow;
#pragma unroll
            for (int r = 0; r < 4; ++r)
                out[((size_t)b * C_ + qrow0 + r) * H_ + col] = o[nf][r] / l4[r];
        }
    } else {
        const int slot = b * SLOTS_B + rr;
        unsigned short* po = PO + (size_t)slot * 64 * 128;
        const int rl0 = wid * 16 + lq * 4;
#pragma unroll
        for (int nf = 0; nf < 8; ++nf) {
            int col = nf * 16 + lrow;
#pragma unroll
            for (int r = 0; r < 4; ++r)
                po[(size_t)(rl0 + r) * 128 + col] = f2bf(o[nf][r]);
        }
        if (lrow == 0) {
            float* ml = ML + (size_t)slot * 128;
#pragma unroll
            for (int r = 0; r < 4; ++r) {
                ml[rl0 + r] = m4[r];
                ml[64 + rl0 + r] = l4[r];
            }
        }
    }
}

// ---------------- combine partials for j >= 4 --------------------------------
__global__ __launch_bounds__(256) void combine_kernel(const unsigned short* __restrict__ PO,
                                                      const float* __restrict__ ML,
                                                      float* __restrict__ out) {
    const int j = blockIdx.x + 4;
    const int b = blockIdx.y;
    const int q = j >> 2, s = j & 3;
    const int Cj = j + 2 * q * (q - 1) + s * q;
    const int nch = q + 1;
    const int base = b * SLOTS_B + Cj;
    const int row = threadIdx.x >> 2;
    const int colg = (threadIdx.x & 3) * 32;

    float mstar = -INFINITY;
    for (int c = 0; c < nch; ++c)
        mstar = fmaxf(mstar, ML[(size_t)(base + c) * 128 + row]);

    float denom = 0.f;
    float acc[32];
#pragma unroll
    for (int i = 0; i < 32; ++i) acc[i] = 0.f;

    for (int c = 0; c < nch; ++c) {
        float mc = ML[(size_t)(base + c) * 128 + row];
        float lc = ML[(size_t)(base + c) * 128 + 64 + row];
        float w = __expf(mc - mstar);
        denom += w * lc;
        const unsigned short* p = PO + (size_t)(base + c) * 64 * 128 + (size_t)row * 128 + colg;
#pragma unroll
        for (int k = 0; k < 4; ++k) {
            bf16x8 v = *(const bf16x8*)&p[k * 8];
#pragma unroll
            for (int e = 0; e < 8; ++e)
                acc[k * 8 + e] += w * bf2f(((unsigned short*)&v)[e]);
        }
    }
    float inv = 1.f / denom;
    float* op = out + ((size_t)b * C_ + j * 64 + row) * H_ + colg;
#pragma unroll
    for (int k = 0; k < 8; ++k) {
        float4 st = {acc[k * 4] * inv, acc[k * 4 + 1] * inv, acc[k * 4 + 2] * inv, acc[k * 4 + 3] * inv};
        *(float4*)&op[k * 4] = st;
    }
}

extern "C" void kernel_launch(void* const* d_in, const int* in_sizes, int n_in,
                              void* d_out, int out_size, void* d_ws, size_t ws_size,
                              hipStream_t stream) {
    const float* x  = (const float*)d_in[0];
    const float* Wq = (const float*)d_in[1];
    const float* Wk = (const float*)d_in[2];
    const float* Wv = (const float*)d_in[3];
    float* out = (float*)d_out;

    unsigned short* WT3 = (unsigned short*)d_ws;                       // 768 KB
    unsigned short* QKV = WT3 + (size_t)3 * H_ * E_;                   // 12 MB (Q, K, V^T)
    unsigned short* PO  = QKV + (size_t)3 * M_ * H_;                   // 18 MB partial O
    float*          ML  = (float*)(PO + (size_t)8 * SLOTS_B * 64 * 128); // 576 KB m,l

    wt3_kernel<<<dim3(64, 3), 256, 0, stream>>>(Wq, Wk, Wv, WT3);

    // --- ablation probes (garbage into QKV; real proj overwrites below) ---
    proj_t<0, 1, 1, 1><<<dim3(M_ / 32), 256, 0, stream>>>(x, WT3, QKV);  // isoB : no B loads
    proj_t<1, 0, 0, 1><<<dim3(M_ / 32), 256, 0, stream>>>(x, WT3, QKV);  // isoA : no A path
    proj_t<1, 1, 0, 1><<<dim3(M_ / 32), 256, 0, stream>>>(x, WT3, QKV);  // isoA2: A gloads, no read/cvt
    proj_t<1, 1, 1, 0><<<dim3(M_ / 32), 256, 0, stream>>>(x, WT3, QKV);  // isoM : no MFMA

    // --- real projection ---
    proj_t<1, 1, 1, 1><<<dim3(M_ / 32), 256, 0, stream>>>(x, WT3, QKV);

    attn_kernel<<<dim3(B_, SLOTS_B), 256, 0, stream>>>(QKV, PO, ML, out);
    combine_kernel<<<dim3(28, B_), 256, 0, stream>>>(PO, ML, out);
}

// Round 19
// 78.000 us; speedup vs baseline: 1.9818x; 1.9818x over previous
//
#include <hip/hip_runtime.h>
#include <hip/hip_bf16.h>
#include <stdint.h>

#define B_ 8
#define C_ 2048
#define E_ 1024
#define H_ 128
#define M_ (B_*C_)      // 16384 rows total
#define SLOTS_B 144     // chunks per batch: sum_j ceil((j+1)/4), j<32

typedef __attribute__((ext_vector_type(8))) short bf16x8;
typedef __attribute__((ext_vector_type(4))) float f32x4;

__device__ __forceinline__ unsigned short f2bf(float f) {
    union { float f; unsigned int u; } v; v.f = f;
    unsigned int u = v.u;
    u += 0x7fff + ((u >> 16) & 1);   // RNE
    return (unsigned short)(u >> 16);
}
__device__ __forceinline__ float bf2f(unsigned short u) {
    union { unsigned int i; float f; } v; v.i = ((unsigned int)u) << 16; return v.f;
}
// pack two floats -> two bf16 (round-half-up) in ONE v_perm + 2 adds
__device__ __forceinline__ unsigned int pack2bf(float lo, float hi) {
    union { float f; unsigned int u; } a, b; a.f = lo; b.f = hi;
    return __builtin_amdgcn_perm(b.u + 0x8000u, a.u + 0x8000u, 0x07060302);
}

#define GLOAD_LDS16(g, l) \
    __builtin_amdgcn_global_load_lds((const __attribute__((address_space(1))) void*)(g), \
                                     (__attribute__((address_space(3))) void*)(l), 16, 0, 0)
// non-temporal variant for streaming sources (aux=2 -> NT on gfx950)
#define GLOAD_LDS16_NT(g, l) \
    __builtin_amdgcn_global_load_lds((const __attribute__((address_space(1))) void*)(g), \
                                     (__attribute__((address_space(3))) void*)(l), 16, 0, 2)

// -------- W -> wave-contiguous fragment layout WT3 --------------------------
__global__ __launch_bounds__(256) void wt3_kernel(const float* __restrict__ Wq,
                                                  const float* __restrict__ Wk,
                                                  const float* __restrict__ Wv,
                                                  unsigned short* __restrict__ WT3) {
    int z = blockIdx.y;
    const float* W = (z == 0) ? Wq : (z == 1) ? Wk : Wv;
    unsigned short* o = WT3 + (size_t)z * H_ * E_;
    int g = blockIdx.x * 256 + threadIdx.x;     // granule id, 0..16383
    int lrow = g & 15;
    int lq   = (g >> 4) & 3;
    int ni   = (g >> 6) & 1;
    int wid  = (g >> 7) & 3;
    int ks   = (g >> 9) & 1;
    int t    = g >> 10;
    int k = t * 64 + ks * 32 + lq * 8;
    int h = wid * 32 + ni * 16 + lrow;
    unsigned short v[8];
#pragma unroll
    for (int j = 0; j < 8; ++j)
        v[j] = f2bf(W[(size_t)(k + j) * H_ + h]);
    *(bf16x8*)&o[(size_t)g * 8] = *(const bf16x8*)v;
}

#define MF(a, b, c) __builtin_amdgcn_mfma_f32_16x16x32_bf16((a), (b), (c), 0, 0, 0)

// ------ fused QKV projection: BM=32, x once. THREE DISTINCT LDS buffers +
// fully-unrolled bodies with literal buffer names -> compiler can prove the
// in-flight gload_lds (buf t+2) doesn't alias the ds_read (buf t), so no
// vmcnt(0) convoy. A prefetch issued AFTER its consumer reads. x loads NT.
#define ASTAGE(ARR, T) { \
    _Pragma("unroll") for (int s_ = 0; s_ < 2; ++s_) { \
        int row_ = s_ * 16 + srow; \
        const float* src_ = x + (size_t)(row0 + row_) * E_ + (T) * 64 \
                          + ((slotL ^ (row_ & 7)) * 4); \
        GLOAD_LDS16_NT(src_, (char*)&ARR[0][0] + s_ * 4096 + tid * 16); } }

#define BODY(T, AR, AP, PF) { \
    __builtin_amdgcn_s_barrier(); \
    __builtin_amdgcn_sched_barrier(0); \
    bf16x8 bw[3][2][2]; \
    { const unsigned short* wp_ = wbase + (size_t)(T) * 8192; \
      _Pragma("unroll") for (int w_ = 0; w_ < 3; ++w_) \
      _Pragma("unroll") for (int ks_ = 0; ks_ < 2; ++ks_) \
      _Pragma("unroll") for (int ni_ = 0; ni_ < 2; ++ni_) \
          bw[w_][ks_][ni_] = *(const bf16x8*)(wp_ + (size_t)w_ * 131072 + ks_ * 4096 + ni_ * 512); } \
    __builtin_amdgcn_sched_barrier(0); \
    bf16x8 af[2][2]; \
    _Pragma("unroll") for (int mi_ = 0; mi_ < 2; ++mi_) \
    _Pragma("unroll") for (int ks_ = 0; ks_ < 2; ++ks_) { \
        int row_ = mi_ * 16 + lrow; \
        int m7_ = row_ & 7; \
        int s0_ = 2 * (ks_ * 4 + lq); \
        f32x4 f0_ = *(const f32x4*)&AR[row_][((s0_)     ^ m7_) * 4]; \
        f32x4 f1_ = *(const f32x4*)&AR[row_][((s0_ + 1) ^ m7_) * 4]; \
        union { unsigned int u[4]; bf16x8 v; } pk_; \
        pk_.u[0] = pack2bf(f0_[0], f0_[1]); \
        pk_.u[1] = pack2bf(f0_[2], f0_[3]); \
        pk_.u[2] = pack2bf(f1_[0], f1_[1]); \
        pk_.u[3] = pack2bf(f1_[2], f1_[3]); \
        af[mi_][ks_] = pk_.v; } \
    __builtin_amdgcn_sched_barrier(0); \
    if (PF) ASTAGE(AP, (T) + 2); \
    __builtin_amdgcn_sched_barrier(0); \
    __builtin_amdgcn_s_setprio(1); \
    _Pragma("unroll") for (int ks_ = 0; ks_ < 2; ++ks_) \
    _Pragma("unroll") for (int w_ = 0; w_ < 3; ++w_) \
    _Pragma("unroll") for (int ni_ = 0; ni_ < 2; ++ni_) \
    _Pragma("unroll") for (int mi_ = 0; mi_ < 2; ++mi_) \
        acc[w_][mi_][ni_] = MF(af[mi_][ks_], bw[w_][ks_][ni_], acc[w_][mi_][ni_]); \
    __builtin_amdgcn_s_setprio(0); }

__global__ __launch_bounds__(256) void proj_kernel(const float* __restrict__ x,
                                                   const unsigned short* __restrict__ WT3,
                                                   unsigned short* __restrict__ QKV) {
    __shared__ __align__(16) float Asf0[32][64];   // 8 KB each, DISTINCT arrays
    __shared__ __align__(16) float Asf1[32][64];
    __shared__ __align__(16) float Asf2[32][64];

    const int tid = threadIdx.x;
    const int wid = tid >> 6, lane = tid & 63;
    const int lrow = lane & 15, lq = lane >> 4;
    const int wcol = wid * 32;          // wave's 32-col slice of H=128
    const int row0 = blockIdx.x * 32;
    const unsigned short* wbase = WT3 + (size_t)wid * 1024 + (size_t)lane * 8;

    const int srow = tid >> 4;          // A staging: row within shot (0..15)
    const int slotL = tid & 15;         // linear LDS 16B-slot

    f32x4 acc[3][2][2];
#pragma unroll
    for (int w = 0; w < 3; ++w)
#pragma unroll
        for (int mi = 0; mi < 2; ++mi)
#pragma unroll
            for (int ni = 0; ni < 2; ++ni) acc[w][mi][ni] = (f32x4){0.f, 0.f, 0.f, 0.f};

    // prologue: tiles 0,1 in flight
    ASTAGE(Asf0, 0);
    ASTAGE(Asf1, 1);

    BODY(0,  Asf0, Asf2, 1)  BODY(1,  Asf1, Asf0, 1)  BODY(2,  Asf2, Asf1, 1)
    BODY(3,  Asf0, Asf2, 1)  BODY(4,  Asf1, Asf0, 1)  BODY(5,  Asf2, Asf1, 1)
    BODY(6,  Asf0, Asf2, 1)  BODY(7,  Asf1, Asf0, 1)  BODY(8,  Asf2, Asf1, 1)
    BODY(9,  Asf0, Asf2, 1)  BODY(10, Asf1, Asf0, 1)  BODY(11, Asf2, Asf1, 1)
    BODY(12, Asf0, Asf2, 1)  BODY(13, Asf1, Asf0, 1)
    BODY(14, Asf2, Asf1, 0)  BODY(15, Asf0, Asf1, 0)

    // epilogue: Q (scaled 1/32), K row-major; V transposed [b][h][c]
#pragma unroll
    for (int w = 0; w < 2; ++w) {
        const float qs = (w == 0) ? 0.03125f : 1.0f;   // fold 1/sqrt(E) into Q
        unsigned short* outp = QKV + (size_t)w * M_ * H_;
#pragma unroll
        for (int mi = 0; mi < 2; ++mi) {
            int r0 = row0 + mi * 16 + lq * 4;
#pragma unroll
            for (int ni = 0; ni < 2; ++ni) {
                int col = wcol + ni * 16 + lrow;
#pragma unroll
                for (int r = 0; r < 4; ++r)
                    outp[(size_t)(r0 + r) * H_ + col] = f2bf(acc[w][mi][ni][r] * qs);
            }
        }
    }
    {
        unsigned short* vt = QKV + (size_t)2 * M_ * H_;
        int b = row0 / C_;
        int cbase = row0 % C_;
#pragma unroll
        for (int mi = 0; mi < 2; ++mi) {
            int c0 = cbase + mi * 16 + lq * 4;
#pragma unroll
            for (int ni = 0; ni < 2; ++ni) {
                int h = wcol + ni * 16 + lrow;
                __align__(8) unsigned short p[4] = {f2bf(acc[2][mi][ni][0]), f2bf(acc[2][mi][ni][1]),
                                                    f2bf(acc[2][mi][ni][2]), f2bf(acc[2][mi][ni][3])};
                *(uint2*)&vt[((size_t)b * H_ + h) * C_ + c0] = *(const uint2*)p;
            }
        }
    }
}

// ---------------- split-KV flash attention, swapped-QK lane-local softmax ----
// grid (B, 144): blockIdx.x = batch -> XCD = b.
__global__ __launch_bounds__(256) void attn_kernel(const unsigned short* __restrict__ QKV,
                                                   unsigned short* __restrict__ PO,
                                                   float* __restrict__ ML,
                                                   float* __restrict__ out) {
    __shared__ __align__(16) unsigned short Ks[2][64][128];
    __shared__ __align__(16) unsigned short Vt[2][128][64];

    const unsigned short* Q  = QKV;
    const unsigned short* K  = QKV + (size_t)M_ * H_;
    const unsigned short* VT = QKV + (size_t)2 * M_ * H_;

    const int tid = threadIdx.x, wid = tid >> 6, lane = tid & 63;
    const int lrow = lane & 15, lq = lane >> 4, lk = lq * 8;
    const int b = blockIdx.x;
    const int rr = blockIdx.y;

    int j = 0;
#pragma unroll
    for (int jj = 1; jj < 32; ++jj) {
        int q = jj >> 2, s = jj & 3;
        if (jj + 2 * q * (q - 1) + s * q <= rr) j = jj;
    }
    const int qj = j >> 2, sj = j & 3;
    const int Cj = j + 2 * qj * (qj - 1) + sj * qj;
    const int c = rr - Cj;
    const int nch = qj + 1;
    const int t0 = c * 4;
    const int t1 = min(t0 + 4, j + 1);

    const int q0w = j * 64 + wid * 16;
    const unsigned short* Kb  = K  + (size_t)b * C_ * H_;
    const unsigned short* VTb = VT + (size_t)b * H_ * C_;
    const int qabs = q0w + lrow;

    const int krow = tid >> 4, kg = tid & 15;
    const int vrow = tid >> 3, vg = tid & 7;

    bf16x8 qf[4];
#pragma unroll
    for (int kf = 0; kf < 4; ++kf)
        qf[kf] = *(const bf16x8*)&Q[((size_t)b * C_ + q0w + lrow) * H_ + kf * 32 + lk];

    f32x4 o[8];
#pragma unroll
    for (int nf = 0; nf < 8; ++nf) o[nf] = (f32x4){0.f, 0.f, 0.f, 0.f};
    float m = -INFINITY, l = 0.f;

    auto STAGE = [&](int buf, int t) {
        const int kv0 = t * 64;
#pragma unroll
        for (int s = 0; s < 4; ++s) {
            int r = s * 16 + krow;
            int prow = ((r & 0x10) << 1) | ((r & 0x0C) << 1) | ((r & 0x20) >> 3) | (r & 3);
            GLOAD_LDS16(&Kb[(size_t)(kv0 + prow) * H_ + ((kg ^ (r & 15)) * 8)],
                        (char*)&Ks[buf][0][0] + s * 4096 + tid * 16);
        }
#pragma unroll
        for (int s = 0; s < 4; ++s) {
            int h = s * 32 + vrow;
            GLOAD_LDS16(&VTb[(size_t)h * C_ + kv0 + ((vg ^ (h & 7)) * 8)],
                        (char*)&Vt[buf][0][0] + s * 4096 + tid * 16);
        }
    };

    STAGE(0, t0);

    for (int t = t0; t < t1; ++t) {
        const int cur = (t - t0) & 1;
        __syncthreads();
        if (t + 1 < t1) STAGE(cur ^ 1, t + 1);

        const int kv0 = t * 64;
        f32x4 s[4];
        __builtin_amdgcn_s_setprio(1);
#pragma unroll
        for (int nf = 0; nf < 4; ++nf) {
            s[nf] = (f32x4){0.f, 0.f, 0.f, 0.f};
            const int rk = nf * 16 + lrow;
#pragma unroll
            for (int kf = 0; kf < 4; ++kf) {
                bf16x8 kb = *(const bf16x8*)&Ks[cur][rk][((kf * 4 + lq) ^ (rk & 15)) * 8];
                s[nf] = __builtin_amdgcn_mfma_f32_16x16x32_bf16(kb, qf[kf], s[nf], 0, 0, 0); // SWAPPED
            }
        }
        __builtin_amdgcn_s_setprio(0);
        bf16x8 vb[8][2];
#pragma unroll
        for (int nf = 0; nf < 8; ++nf) {
            const int h = nf * 16 + lrow;
#pragma unroll
            for (int kf2 = 0; kf2 < 2; ++kf2)
                vb[nf][kf2] = *(const bf16x8*)&Vt[cur][h][((kf2 * 4 + lq) ^ (h & 7)) * 8];
        }

        if (t == j) {
#pragma unroll
            for (int nf = 0; nf < 4; ++nf) {
                int kvb = kv0 + ((nf & 1) << 5) + (lq << 3) + ((nf >> 1) << 2);
#pragma unroll
                for (int r = 0; r < 4; ++r)
                    if (kvb + r > qabs) s[nf][r] = -INFINITY;
            }
        }
        float mt = s[0][0];
#pragma unroll
        for (int nf = 0; nf < 4; ++nf)
#pragma unroll
            for (int r = 0; r < 4; ++r) mt = fmaxf(mt, s[nf][r]);
        mt = fmaxf(mt, __shfl_xor(mt, 16));
        mt = fmaxf(mt, __shfl_xor(mt, 32));

        float mn = fmaxf(m, mt);
        float corr = __expf(m - mn);
        m = mn;

        float p[4][4];
        float ps = 0.f;
#pragma unroll
        for (int nf = 0; nf < 4; ++nf)
#pragma unroll
            for (int r = 0; r < 4; ++r) {
                float e = __expf(s[nf][r] - mn);
                p[nf][r] = e;
                ps += e;
            }
        ps += __shfl_xor(ps, 16);
        ps += __shfl_xor(ps, 32);
        l = l * corr + ps;

        float corr4[4];
#pragma unroll
        for (int r = 0; r < 4; ++r)
            corr4[r] = __shfl(corr, (lane & 48) | (lq * 4 + r));
#pragma unroll
        for (int nf = 0; nf < 8; ++nf)
#pragma unroll
            for (int r = 0; r < 4; ++r) o[nf][r] *= corr4[r];

        bf16x8 pa[2];
#pragma unroll
        for (int kf2 = 0; kf2 < 2; ++kf2) {
            union { unsigned int u[4]; bf16x8 v; } pk;
            pk.u[0] = pack2bf(p[kf2][0],     p[kf2][1]);
            pk.u[1] = pack2bf(p[kf2][2],     p[kf2][3]);
            pk.u[2] = pack2bf(p[kf2 + 2][0], p[kf2 + 2][1]);
            pk.u[3] = pack2bf(p[kf2 + 2][2], p[kf2 + 2][3]);
            pa[kf2] = pk.v;
        }
        __builtin_amdgcn_s_setprio(1);
#pragma unroll
        for (int nf = 0; nf < 8; ++nf)
#pragma unroll
            for (int kf2 = 0; kf2 < 2; ++kf2)
                o[nf] = __builtin_amdgcn_mfma_f32_16x16x32_bf16(pa[kf2], vb[nf][kf2], o[nf], 0, 0, 0);
        __builtin_amdgcn_s_setprio(0);
    }

    float l4[4], m4[4];
#pragma unroll
    for (int r = 0; r < 4; ++r) {
        l4[r] = __shfl(l, (lane & 48) | (lq * 4 + r));
        m4[r] = __shfl(m, (lane & 48) | (lq * 4 + r));
    }
    const int qrow0 = q0w + lq * 4;

    if (nch == 1) {
#pragma unroll
        for (int nf = 0; nf < 8; ++nf) {
            int col = nf * 16 + lrow;
#pragma unroll
            for (int r = 0; r < 4; ++r)
                out[((size_t)b * C_ + qrow0 + r) * H_ + col] = o[nf][r] / l4[r];
        }
    } else {
        const int slot = b * SLOTS_B + rr;
        unsigned short* po = PO + (size_t)slot * 64 * 128;
        const int rl0 = wid * 16 + lq * 4;
#pragma unroll
        for (int nf = 0; nf < 8; ++nf) {
            int col = nf * 16 + lrow;
#pragma unroll
            for (int r = 0; r < 4; ++r)
                po[(size_t)(rl0 + r) * 128 + col] = f2bf(o[nf][r]);
        }
        if (lrow == 0) {
            float* ml = ML + (size_t)slot * 128;
#pragma unroll
            for (int r = 0; r < 4; ++r) {
                ml[rl0 + r] = m4[r];
                ml[64 + rl0 + r] = l4[r];
            }
        }
    }
}

// ---------------- combine partials for j >= 4 --------------------------------
__global__ __launch_bounds__(256) void combine_kernel(const unsigned short* __restrict__ PO,
                                                      const float* __restrict__ ML,
                                                      float* __restrict__ out) {
    const int j = blockIdx.x + 4;
    const int b = blockIdx.y;
    const int q = j >> 2, s = j & 3;
    const int Cj = j + 2 * q * (q - 1) + s * q;
    const int nch = q + 1;
    const int base = b * SLOTS_B + Cj;
    const int row = threadIdx.x >> 2;
    const int colg = (threadIdx.x & 3) * 32;

    float mstar = -INFINITY;
    for (int c = 0; c < nch; ++c)
        mstar = fmaxf(mstar, ML[(size_t)(base + c) * 128 + row]);

    float denom = 0.f;
    float acc[32];
#pragma unroll
    for (int i = 0; i < 32; ++i) acc[i] = 0.f;

    for (int c = 0; c < nch; ++c) {
        float mc = ML[(size_t)(base + c) * 128 + row];
        float lc = ML[(size_t)(base + c) * 128 + 64 + row];
        float w = __expf(mc - mstar);
        denom += w * lc;
        const unsigned short* p = PO + (size_t)(base + c) * 64 * 128 + (size_t)row * 128 + colg;
#pragma unroll
        for (int k = 0; k < 4; ++k) {
            bf16x8 v = *(const bf16x8*)&p[k * 8];
#pragma unroll
            for (int e = 0; e < 8; ++e)
                acc[k * 8 + e] += w * bf2f(((unsigned short*)&v)[e]);
        }
    }
    float inv = 1.f / denom;
    float* op = out + ((size_t)b * C_ + j * 64 + row) * H_ + colg;
#pragma unroll
    for (int k = 0; k < 8; ++k) {
        float4 st = {acc[k * 4] * inv, acc[k * 4 + 1] * inv, acc[k * 4 + 2] * inv, acc[k * 4 + 3] * inv};
        *(float4*)&op[k * 4] = st;
    }
}

extern "C" void kernel_launch(void* const* d_in, const int* in_sizes, int n_in,
                              void* d_out, int out_size, void* d_ws, size_t ws_size,
                              hipStream_t stream) {
    const float* x  = (const float*)d_in[0];
    const float* Wq = (const float*)d_in[1];
    const float* Wk = (const float*)d_in[2];
    const float* Wv = (const float*)d_in[3];
    float* out = (float*)d_out;

    unsigned short* WT3 = (unsigned short*)d_ws;                       // 768 KB
    unsigned short* QKV = WT3 + (size_t)3 * H_ * E_;                   // 12 MB (Q, K, V^T)
    unsigned short* PO  = QKV + (size_t)3 * M_ * H_;                   // 18 MB partial O
    float*          ML  = (float*)(PO + (size_t)8 * SLOTS_B * 64 * 128); // 576 KB m,l

    wt3_kernel<<<dim3(64, 3), 256, 0, stream>>>(Wq, Wk, Wv, WT3);
    proj_kernel<<<dim3(M_ / 32), 256, 0, stream>>>(x, WT3, QKV);
    attn_kernel<<<dim3(B_, SLOTS_B), 256, 0, stream>>>(QKV, PO, ML, out);
    combine_kernel<<<dim3(28, B_), 256, 0, stream>>>(PO, ML, out);
}

// Round 20
// 70.309 us; speedup vs baseline: 2.1986x; 1.1094x over previous
//
#include <hip/hip_runtime.h>
#include <hip/hip_bf16.h>
#include <stdint.h>

#define B_ 8
#define C_ 2048
#define E_ 1024
#define H_ 128
#define M_ (B_*C_)      // 16384 rows total
#define SLOTS_B 144     // chunks per batch: sum_j ceil((j+1)/4), j<32

typedef __attribute__((ext_vector_type(8))) short bf16x8;
typedef __attribute__((ext_vector_type(4))) float f32x4;

__device__ __forceinline__ unsigned short f2bf(float f) {
    union { float f; unsigned int u; } v; v.f = f;
    unsigned int u = v.u;
    u += 0x7fff + ((u >> 16) & 1);   // RNE
    return (unsigned short)(u >> 16);
}
__device__ __forceinline__ float bf2f(unsigned short u) {
    union { unsigned int i; float f; } v; v.i = ((unsigned int)u) << 16; return v.f;
}
// pack two floats -> two bf16 (round-half-up) in ONE v_perm + 2 adds
__device__ __forceinline__ unsigned int pack2bf(float lo, float hi) {
    union { float f; unsigned int u; } a, b; a.f = lo; b.f = hi;
    return __builtin_amdgcn_perm(b.u + 0x8000u, a.u + 0x8000u, 0x07060302);
}

#define GLOAD_LDS16(g, l) \
    __builtin_amdgcn_global_load_lds((const __attribute__((address_space(1))) void*)(g), \
                                     (__attribute__((address_space(3))) void*)(l), 16, 0, 0)

// -------- W -> fragment-ordered bf16: WT2[w][g*128 + h] = 16B granule -------
__global__ __launch_bounds__(256) void wt2_kernel(const float* __restrict__ Wq,
                                                  const float* __restrict__ Wk,
                                                  const float* __restrict__ Wv,
                                                  unsigned short* __restrict__ WT2) {
    int z = blockIdx.y;
    const float* W = (z == 0) ? Wq : (z == 1) ? Wk : Wv;
    unsigned short* o = WT2 + (size_t)z * H_ * E_;
    int gid = blockIdx.x * 256 + threadIdx.x;   // over (E_/8)*H_ = 16384 granules
    int g = gid >> 7, h = gid & 127;
    unsigned short t[8];
#pragma unroll
    for (int j = 0; j < 8; ++j)
        t[j] = f2bf(W[(size_t)(g * 8 + j) * H_ + h]);
    *(bf16x8*)&o[(size_t)(g * 128 + h) * 8] = *(const bf16x8*)t;
}

// ------ fused QKV projection (best measured): BM=32, x once ------------------
#define MF(a, b, c) __builtin_amdgcn_mfma_f32_16x16x32_bf16((a), (b), (c), 0, 0, 0)

#define ALOAD(S, T) { const float* xs_ = xrow + (T) * 64; \
    a##S##_0 = *(const float4*)xs_;  a##S##_1 = *(const float4*)(xs_ + 4); }

#define AWRITE(S, BUF) { \
    unsigned short t_[8] = {f2bf(a##S##_0.x), f2bf(a##S##_0.y), f2bf(a##S##_0.z), f2bf(a##S##_0.w), \
                            f2bf(a##S##_1.x), f2bf(a##S##_1.y), f2bf(a##S##_1.z), f2bf(a##S##_1.w)}; \
    *(bf16x8*)&As[BUF][arow][(ag ^ (arow & 7)) * 8] = *(const bf16x8*)t_; }

#define BLOAD(S, T) { const unsigned short* wp_ = wbase + (size_t)(T) * 8192; \
    b##S##0  = *(const bf16x8*)(wp_);            b##S##1  = *(const bf16x8*)(wp_ + 128); \
    b##S##2  = *(const bf16x8*)(wp_ + 4096);     b##S##3  = *(const bf16x8*)(wp_ + 4224); \
    b##S##4  = *(const bf16x8*)(wp_ + 131072);   b##S##5  = *(const bf16x8*)(wp_ + 131200); \
    b##S##6  = *(const bf16x8*)(wp_ + 135168);   b##S##7  = *(const bf16x8*)(wp_ + 135296); \
    b##S##8  = *(const bf16x8*)(wp_ + 262144);   b##S##9  = *(const bf16x8*)(wp_ + 262272); \
    b##S##10 = *(const bf16x8*)(wp_ + 266240);   b##S##11 = *(const bf16x8*)(wp_ + 266368); }

#define COMPUTE(BUF, S) { \
    bf16x8 af00 = *(const bf16x8*)&As[BUF][ra0][(lq ^ (ra0 & 7)) * 8]; \
    bf16x8 af10 = *(const bf16x8*)&As[BUF][ra1][(lq ^ (ra1 & 7)) * 8]; \
    acc[0][0][0] = MF(af00, b##S##0, acc[0][0][0]);  acc[0][1][0] = MF(af10, b##S##0, acc[0][1][0]); \
    acc[0][0][1] = MF(af00, b##S##1, acc[0][0][1]);  acc[0][1][1] = MF(af10, b##S##1, acc[0][1][1]); \
    acc[1][0][0] = MF(af00, b##S##4, acc[1][0][0]);  acc[1][1][0] = MF(af10, b##S##4, acc[1][1][0]); \
    acc[1][0][1] = MF(af00, b##S##5, acc[1][0][1]);  acc[1][1][1] = MF(af10, b##S##5, acc[1][1][1]); \
    acc[2][0][0] = MF(af00, b##S##8, acc[2][0][0]);  acc[2][1][0] = MF(af10, b##S##8, acc[2][1][0]); \
    acc[2][0][1] = MF(af00, b##S##9, acc[2][0][1]);  acc[2][1][1] = MF(af10, b##S##9, acc[2][1][1]); \
    bf16x8 af01 = *(const bf16x8*)&As[BUF][ra0][((4 + lq) ^ (ra0 & 7)) * 8]; \
    bf16x8 af11 = *(const bf16x8*)&As[BUF][ra1][((4 + lq) ^ (ra1 & 7)) * 8]; \
    acc[0][0][0] = MF(af01, b##S##2, acc[0][0][0]);  acc[0][1][0] = MF(af11, b##S##2, acc[0][1][0]); \
    acc[0][0][1] = MF(af01, b##S##3, acc[0][0][1]);  acc[0][1][1] = MF(af11, b##S##3, acc[0][1][1]); \
    acc[1][0][0] = MF(af01, b##S##6, acc[1][0][0]);  acc[1][1][0] = MF(af11, b##S##6, acc[1][1][0]); \
    acc[1][0][1] = MF(af01, b##S##7, acc[1][0][1]);  acc[1][1][1] = MF(af11, b##S##7, acc[1][1][1]); \
    acc[2][0][0] = MF(af01, b##S##10, acc[2][0][0]); acc[2][1][0] = MF(af11, b##S##10, acc[2][1][0]); \
    acc[2][0][1] = MF(af01, b##S##11, acc[2][0][1]); acc[2][1][1] = MF(af11, b##S##11, acc[2][1][1]); }

#define STEP_E(K) { __syncthreads(); \
    if ((K) < 15) { ALOAD(O, (K)+1); BLOAD(O, (K)+1); } \
    COMPUTE((K)&1, E); \
    if ((K) < 15) AWRITE(O, ((K)+1)&1); }

#define STEP_O(K) { __syncthreads(); \
    if ((K) < 15) { ALOAD(E, (K)+1); BLOAD(E, (K)+1); } \
    COMPUTE((K)&1, O); \
    if ((K) < 15) AWRITE(E, ((K)+1)&1); }

__global__ __launch_bounds__(256) void proj_kernel(const float* __restrict__ x,
                                                   const unsigned short* __restrict__ WT2,
                                                   unsigned short* __restrict__ QKV) {
    __shared__ __align__(16) unsigned short As[2][32][64];    // 8 KB dbuf, XOR-swz

    const int tid = threadIdx.x;
    const int wid = tid >> 6, lane = tid & 63;
    const int lrow = lane & 15, lq = lane >> 4;
    const int wcol = wid * 32;
    const int row0 = blockIdx.x * 32;

    const int arow = tid >> 3;
    const int ag = tid & 7;
    const float* xrow = x + (size_t)(row0 + arow) * E_ + ag * 8;
    const int ra0 = lrow, ra1 = 16 + lrow;
    const unsigned short* wbase = WT2 + (size_t)(lq * 128 + wcol + lrow) * 8;

    f32x4 acc[3][2][2];
#pragma unroll
    for (int w = 0; w < 3; ++w)
#pragma unroll
        for (int mi = 0; mi < 2; ++mi)
#pragma unroll
            for (int ni = 0; ni < 2; ++ni) acc[w][mi][ni] = (f32x4){0.f, 0.f, 0.f, 0.f};

    float4 aE_0, aE_1, aO_0, aO_1;
    bf16x8 bE0, bE1, bE2, bE3, bE4, bE5, bE6, bE7, bE8, bE9, bE10, bE11;
    bf16x8 bO0, bO1, bO2, bO3, bO4, bO5, bO6, bO7, bO8, bO9, bO10, bO11;

    ALOAD(E, 0); BLOAD(E, 0);
    AWRITE(E, 0);

    STEP_E(0)  STEP_O(1)  STEP_E(2)  STEP_O(3)
    STEP_E(4)  STEP_O(5)  STEP_E(6)  STEP_O(7)
    STEP_E(8)  STEP_O(9)  STEP_E(10) STEP_O(11)
    STEP_E(12) STEP_O(13) STEP_E(14) STEP_O(15)

#pragma unroll
    for (int w = 0; w < 2; ++w) {
        const float qs = (w == 0) ? 0.03125f : 1.0f;   // fold 1/sqrt(E) into Q
        unsigned short* outp = QKV + (size_t)w * M_ * H_;
#pragma unroll
        for (int mi = 0; mi < 2; ++mi) {
            int r0 = row0 + mi * 16 + lq * 4;
#pragma unroll
            for (int ni = 0; ni < 2; ++ni) {
                int col = wcol + ni * 16 + lrow;
#pragma unroll
                for (int r = 0; r < 4; ++r)
                    outp[(size_t)(r0 + r) * H_ + col] = f2bf(acc[w][mi][ni][r] * qs);
            }
        }
    }
    {
        unsigned short* vt = QKV + (size_t)2 * M_ * H_;
        int b = row0 / C_;
        int cbase = row0 % C_;
#pragma unroll
        for (int mi = 0; mi < 2; ++mi) {
            int c0 = cbase + mi * 16 + lq * 4;
#pragma unroll
            for (int ni = 0; ni < 2; ++ni) {
                int h = wcol + ni * 16 + lrow;
                __align__(8) unsigned short p[4] = {f2bf(acc[2][mi][ni][0]), f2bf(acc[2][mi][ni][1]),
                                                    f2bf(acc[2][mi][ni][2]), f2bf(acc[2][mi][ni][3])};
                *(uint2*)&vt[((size_t)b * H_ + h) * C_ + c0] = *(const uint2*)p;
            }
        }
    }
}

// ---------------- split-KV flash attention, swapped-QK lane-local softmax ----
// grid (B, 144): blockIdx.x = batch -> XCD = b.
// K staged with row bit-permutation pi so each lane's P values are exactly its
// PV A-fragment: pi(R) = [b4 b3 b2 b5 b1 b0].
__global__ __launch_bounds__(256) void attn_kernel(const unsigned short* __restrict__ QKV,
                                                   unsigned short* __restrict__ PO,
                                                   float* __restrict__ ML,
                                                   float* __restrict__ out) {
    __shared__ __align__(16) unsigned short Ks[2][64][128];
    __shared__ __align__(16) unsigned short Vt[2][128][64];

    const unsigned short* Q  = QKV;
    const unsigned short* K  = QKV + (size_t)M_ * H_;
    const unsigned short* VT = QKV + (size_t)2 * M_ * H_;

    const int tid = threadIdx.x, wid = tid >> 6, lane = tid & 63;
    const int lrow = lane & 15, lq = lane >> 4, lk = lq * 8;
    const int b = blockIdx.x;
    const int rr = blockIdx.y;

    int j = 0;
#pragma unroll
    for (int jj = 1; jj < 32; ++jj) {
        int q = jj >> 2, s = jj & 3;
        if (jj + 2 * q * (q - 1) + s * q <= rr) j = jj;
    }
    const int qj = j >> 2, sj = j & 3;
    const int Cj = j + 2 * qj * (qj - 1) + sj * qj;
    const int c = rr - Cj;
    const int nch = qj + 1;
    const int t0 = c * 4;
    const int t1 = min(t0 + 4, j + 1);

    const int q0w = j * 64 + wid * 16;
    const unsigned short* Kb  = K  + (size_t)b * C_ * H_;
    const unsigned short* VTb = VT + (size_t)b * H_ * C_;
    const int qabs = q0w + lrow;        // this lane's q row (softmax space)

    const int krow = tid >> 4, kg = tid & 15;
    const int vrow = tid >> 3, vg = tid & 7;

    bf16x8 qf[4];
#pragma unroll
    for (int kf = 0; kf < 4; ++kf)
        qf[kf] = *(const bf16x8*)&Q[((size_t)b * C_ + q0w + lrow) * H_ + kf * 32 + lk];

    f32x4 o[8];
#pragma unroll
    for (int nf = 0; nf < 8; ++nf) o[nf] = (f32x4){0.f, 0.f, 0.f, 0.f};
    float m = -INFINITY, l = 0.f;       // scalar state for q = qabs

    auto STAGE = [&](int buf, int t) {
        const int kv0 = t * 64;
#pragma unroll
        for (int s = 0; s < 4; ++s) {
            int r = s * 16 + krow;      // LDS row
            int prow = ((r & 0x10) << 1) | ((r & 0x0C) << 1) | ((r & 0x20) >> 3) | (r & 3);
            GLOAD_LDS16(&Kb[(size_t)(kv0 + prow) * H_ + ((kg ^ (r & 15)) * 8)],
                        (char*)&Ks[buf][0][0] + s * 4096 + tid * 16);
        }
#pragma unroll
        for (int s = 0; s < 4; ++s) {
            int h = s * 32 + vrow;
            GLOAD_LDS16(&VTb[(size_t)h * C_ + kv0 + ((vg ^ (h & 7)) * 8)],
                        (char*)&Vt[buf][0][0] + s * 4096 + tid * 16);
        }
    };

    STAGE(0, t0);

    for (int t = t0; t < t1; ++t) {
        const int cur = (t - t0) & 1;
        __syncthreads();
        if (t + 1 < t1) STAGE(cur ^ 1, t + 1);

        const int kv0 = t * 64;
        f32x4 s[4];
        __builtin_amdgcn_s_setprio(1);
#pragma unroll
        for (int nf = 0; nf < 4; ++nf) {
            s[nf] = (f32x4){0.f, 0.f, 0.f, 0.f};
            const int rk = nf * 16 + lrow;
#pragma unroll
            for (int kf = 0; kf < 4; ++kf) {
                bf16x8 kb = *(const bf16x8*)&Ks[cur][rk][((kf * 4 + lq) ^ (rk & 15)) * 8];
                s[nf] = __builtin_amdgcn_mfma_f32_16x16x32_bf16(kb, qf[kf], s[nf], 0, 0, 0); // SWAPPED
            }
        }
        __builtin_amdgcn_s_setprio(0);
        bf16x8 vb[8][2];
#pragma unroll
        for (int nf = 0; nf < 8; ++nf) {
            const int h = nf * 16 + lrow;
#pragma unroll
            for (int kf2 = 0; kf2 < 2; ++kf2)
                vb[nf][kf2] = *(const bf16x8*)&Vt[cur][h][((kf2 * 4 + lq) ^ (h & 7)) * 8];
        }

        // lane holds S[kv][q=qabs]; kv = kv0 + (nf&1)*32 + lq*8 + (nf>>1)*4 + r
        if (t == j) {
#pragma unroll
            for (int nf = 0; nf < 4; ++nf) {
                int kvb = kv0 + ((nf & 1) << 5) + (lq << 3) + ((nf >> 1) << 2);
#pragma unroll
                for (int r = 0; r < 4; ++r)
                    if (kvb + r > qabs) s[nf][r] = -INFINITY;
            }
        }
        // in-lane max over 16 + 2-hop cross-lq reduce
        float mt = s[0][0];
#pragma unroll
        for (int nf = 0; nf < 4; ++nf)
#pragma unroll
            for (int r = 0; r < 4; ++r) mt = fmaxf(mt, s[nf][r]);
        mt = fmaxf(mt, __shfl_xor(mt, 16));
        mt = fmaxf(mt, __shfl_xor(mt, 32));

        float mn = fmaxf(m, mt);
        float corr = __expf(m - mn);    // first tile: exp(-inf)=0
        m = mn;

        float p[4][4];
        float ps = 0.f;
#pragma unroll
        for (int nf = 0; nf < 4; ++nf)
#pragma unroll
            for (int r = 0; r < 4; ++r) {
                float e = __expf(s[nf][r] - mn);   // masked -> 0
                p[nf][r] = e;
                ps += e;
            }
        ps += __shfl_xor(ps, 16);
        ps += __shfl_xor(ps, 32);
        l = l * corr + ps;

        // redistribute corr to D-row space (row q = lq*4+r)
        float corr4[4];
#pragma unroll
        for (int r = 0; r < 4; ++r)
            corr4[r] = __shfl(corr, (lane & 48) | (lq * 4 + r));
#pragma unroll
        for (int nf = 0; nf < 8; ++nf)
#pragma unroll
            for (int r = 0; r < 4; ++r) o[nf][r] *= corr4[r];

        // in-register P -> A-frag pack (permuted-K makes this exact)
        bf16x8 pa[2];
#pragma unroll
        for (int kf2 = 0; kf2 < 2; ++kf2) {
            union { unsigned int u[4]; bf16x8 v; } pk;
            pk.u[0] = pack2bf(p[kf2][0],     p[kf2][1]);
            pk.u[1] = pack2bf(p[kf2][2],     p[kf2][3]);
            pk.u[2] = pack2bf(p[kf2 + 2][0], p[kf2 + 2][1]);
            pk.u[3] = pack2bf(p[kf2 + 2][2], p[kf2 + 2][3]);
            pa[kf2] = pk.v;
        }
        __builtin_amdgcn_s_setprio(1);
#pragma unroll
        for (int nf = 0; nf < 8; ++nf)
#pragma unroll
            for (int kf2 = 0; kf2 < 2; ++kf2)
                o[nf] = __builtin_amdgcn_mfma_f32_16x16x32_bf16(pa[kf2], vb[nf][kf2], o[nf], 0, 0, 0);
        __builtin_amdgcn_s_setprio(0);
    }

    // redistribute l (and m) from softmax space (q=lane&15) to D-row space
    float l4[4], m4[4];
#pragma unroll
    for (int r = 0; r < 4; ++r) {
        l4[r] = __shfl(l, (lane & 48) | (lq * 4 + r));
        m4[r] = __shfl(m, (lane & 48) | (lq * 4 + r));
    }
    const int qrow0 = q0w + lq * 4;

    if (nch == 1) {       // j <= 3: single chunk, write normalized
#pragma unroll
        for (int nf = 0; nf < 8; ++nf) {
            int col = nf * 16 + lrow;
#pragma unroll
            for (int r = 0; r < 4; ++r)
                out[((size_t)b * C_ + qrow0 + r) * H_ + col] = o[nf][r] / l4[r];
        }
    } else {              // partial: O (bf16, unnormalized) + m,l
        const int slot = b * SLOTS_B + rr;
        unsigned short* po = PO + (size_t)slot * 64 * 128;
        const int rl0 = wid * 16 + lq * 4;
#pragma unroll
        for (int nf = 0; nf < 8; ++nf) {
            int col = nf * 16 + lrow;
#pragma unroll
            for (int r = 0; r < 4; ++r)
                po[(size_t)(rl0 + r) * 128 + col] = f2bf(o[nf][r]);
        }
        if (lrow == 0) {
            float* ml = ML + (size_t)slot * 128;
#pragma unroll
            for (int r = 0; r < 4; ++r) {
                ml[rl0 + r] = m4[r];
                ml[64 + rl0 + r] = l4[r];
            }
        }
    }
}

// ---------------- combine partials for j >= 4 --------------------------------
__global__ __launch_bounds__(256) void combine_kernel(const unsigned short* __restrict__ PO,
                                                      const float* __restrict__ ML,
                                                      float* __restrict__ out) {
    const int j = blockIdx.x + 4;
    const int b = blockIdx.y;
    const int q = j >> 2, s = j & 3;
    const int Cj = j + 2 * q * (q - 1) + s * q;
    const int nch = q + 1;
    const int base = b * SLOTS_B + Cj;
    const int row = threadIdx.x >> 2;
    const int colg = (threadIdx.x & 3) * 32;

    float mstar = -INFINITY;
    for (int c = 0; c < nch; ++c)
        mstar = fmaxf(mstar, ML[(size_t)(base + c) * 128 + row]);

    float denom = 0.f;
    float acc[32];
#pragma unroll
    for (int i = 0; i < 32; ++i) acc[i] = 0.f;

    for (int c = 0; c < nch; ++c) {
        float mc = ML[(size_t)(base + c) * 128 + row];
        float lc = ML[(size_t)(base + c) * 128 + 64 + row];
        float w = __expf(mc - mstar);
        denom += w * lc;
        const unsigned short* p = PO + (size_t)(base + c) * 64 * 128 + (size_t)row * 128 + colg;
#pragma unroll
        for (int k = 0; k < 4; ++k) {
            bf16x8 v = *(const bf16x8*)&p[k * 8];
#pragma unroll
            for (int e = 0; e < 8; ++e)
                acc[k * 8 + e] += w * bf2f(((unsigned short*)&v)[e]);
        }
    }
    float inv = 1.f / denom;
    float* op = out + ((size_t)b * C_ + j * 64 + row) * H_ + colg;
#pragma unroll
    for (int k = 0; k < 8; ++k) {
        float4 st = {acc[k * 4] * inv, acc[k * 4 + 1] * inv, acc[k * 4 + 2] * inv, acc[k * 4 + 3] * inv};
        *(float4*)&op[k * 4] = st;
    }
}

extern "C" void kernel_launch(void* const* d_in, const int* in_sizes, int n_in,
                              void* d_out, int out_size, void* d_ws, size_t ws_size,
                              hipStream_t stream) {
    const float* x  = (const float*)d_in[0];
    const float* Wq = (const float*)d_in[1];
    const float* Wk = (const float*)d_in[2];
    const float* Wv = (const float*)d_in[3];
    float* out = (float*)d_out;

    unsigned short* WT2 = (unsigned short*)d_ws;                       // 768 KB
    unsigned short* QKV = WT2 + (size_t)3 * H_ * E_;                   // 12 MB (Q, K, V^T)
    unsigned short* PO  = QKV + (size_t)3 * M_ * H_;                   // 18 MB partial O
    float*          ML  = (float*)(PO + (size_t)8 * SLOTS_B * 64 * 128); // 576 KB m,l

    wt2_kernel<<<dim3(E_ / 8 * H_ / 256, 3), 256, 0, stream>>>(Wq, Wk, Wv, WT2);
    proj_kernel<<<dim3(M_ / 32), 256, 0, stream>>>(x, WT2, QKV);
    attn_kernel<<<dim3(B_, SLOTS_B), 256, 0, stream>>>(QKV, PO, ML, out);
    combine_kernel<<<dim3(28, B_), 256, 0, stream>>>(PO, ML, out);
}